// Round 9
// baseline (534.750 us; speedup 1.0000x reference)
//
#include <hip/hip_runtime.h>
#include <hip/hip_bf16.h>

#define NN 100000
#define NE 1600000
#define NF 128
#define NG 128
#define NC 10

#define NCH 782        // 128-node chunks: 782*128 = 100096 >= NN
#define PBLK 128       // partition blocks
#define EPB 12500      // edges per partition block (128*12500 = NE exactly)

typedef short short8 __attribute__((ext_vector_type(8)));
typedef float f32x4 __attribute__((ext_vector_type(4)));

__device__ inline unsigned short f2bf(float x) {
    unsigned u = __float_as_uint(x);
    u += 0x7FFF + ((u >> 16) & 1);          // round-to-nearest-even
    return (unsigned short)(u >> 16);
}
__device__ inline float bf2f(unsigned short h) {
    return __uint_as_float(((unsigned)h) << 16);
}
__device__ inline float bfu_lo(unsigned v) { return __uint_as_float(v << 16); }
__device__ inline float bfu_hi(unsigned v) { return __uint_as_float(v & 0xffff0000u); }
__device__ inline unsigned bfu_pack(float lo, float hi) {
    return (unsigned)f2bf(lo) | ((unsigned)f2bf(hi) << 16);
}

// ================= CSR build: two-level counting sort, NO global atomics =================

__global__ __launch_bounds__(256) void k_phist(const int* __restrict__ dst,
                                               unsigned* __restrict__ mat) {
    __shared__ unsigned lh[NCH];
    for (int i = threadIdx.x; i < NCH; i += 256) lh[i] = 0;
    __syncthreads();
    int base = blockIdx.x * EPB;
    for (int i = threadIdx.x; i < EPB; i += 256)
        atomicAdd(&lh[dst[base + i] >> 7], 1u);
    __syncthreads();
    for (int i = threadIdx.x; i < NCH; i += 256)
        mat[(size_t)blockIdx.x * NCH + i] = lh[i];
}

__global__ __launch_bounds__(PBLK) void k_cscan(unsigned* __restrict__ mat,
                                                unsigned* __restrict__ ctot) {
    __shared__ unsigned s[PBLK];
    int ch = blockIdx.x;
    int t  = threadIdx.x;
    unsigned v = mat[(size_t)t * NCH + ch];
    s[t] = v;
    __syncthreads();
    for (int off = 1; off < PBLK; off <<= 1) {
        unsigned u = (t >= off) ? s[t - off] : 0;
        __syncthreads();
        s[t] += u;
        __syncthreads();
    }
    mat[(size_t)t * NCH + ch] = s[t] - v;
    if (t == PBLK - 1) ctot[ch] = s[t];
}

__global__ __launch_bounds__(1024) void k_cbase(const unsigned* __restrict__ ctot,
                                                unsigned* __restrict__ cbase) {
    __shared__ unsigned s[1024];
    int t = threadIdx.x;
    unsigned v = (t < NCH) ? ctot[t] : 0;
    s[t] = v;
    __syncthreads();
    for (int off = 1; off < 1024; off <<= 1) {
        unsigned u = (t >= off) ? s[t - off] : 0;
        __syncthreads();
        s[t] += u;
        __syncthreads();
    }
    if (t < NCH) cbase[t] = s[t] - v;
    if (t == NCH - 1) cbase[NCH] = s[t];
}

__global__ __launch_bounds__(256) void k_pscat(const int* __restrict__ src,
                                               const int* __restrict__ dst,
                                               const float* __restrict__ ew,
                                               const unsigned* __restrict__ mat,
                                               const unsigned* __restrict__ cbase,
                                               int2* __restrict__ eparts) {
    __shared__ unsigned cur[NCH];
    for (int i = threadIdx.x; i < NCH; i += 256)
        cur[i] = cbase[i] + mat[(size_t)blockIdx.x * NCH + i];
    __syncthreads();
    int base = blockIdx.x * EPB;
    for (int i = threadIdx.x; i < EPB; i += 256) {
        int e = base + i;
        int d = dst[e], s = src[e];
        float w = ew[e];
        unsigned pos = atomicAdd(&cur[d >> 7], 1u);   // LDS atomic
        eparts[pos] = make_int2(s | ((d & 127) << 20), __float_as_int(w));
    }
}

__global__ __launch_bounds__(256) void k_csort(const unsigned* __restrict__ cbase,
                                               const int2* __restrict__ eparts,
                                               int2* __restrict__ efinal,
                                               int* __restrict__ rowstart,
                                               int* __restrict__ cnt,
                                               float* __restrict__ dinv) {
    __shared__ unsigned nh[128];
    __shared__ float    ws[128];
    __shared__ unsigned sc[128];
    __shared__ unsigned cur[128];
    int ch = blockIdx.x;
    unsigned beg = cbase[ch], end = cbase[ch + 1];
    int t = threadIdx.x;
    if (t < 128) { nh[t] = 0; ws[t] = 0.f; }
    __syncthreads();
    for (unsigned i = beg + t; i < end; i += 256) {
        int2 ep = eparts[i];
        int n = (ep.x >> 20) & 127;
        atomicAdd(&nh[n], 1u);
        atomicAdd(&ws[n], __int_as_float(ep.y));
    }
    __syncthreads();
    unsigned v = (t < 128) ? nh[t] : 0;
    if (t < 128) sc[t] = v;
    __syncthreads();
    for (int off = 1; off < 128; off <<= 1) {
        unsigned u = (t >= off && t < 128) ? sc[t - off] : 0;
        __syncthreads();
        if (t < 128) sc[t] += u;
        __syncthreads();
    }
    if (t < 128) {
        int node = ch * 128 + t;
        if (node < NN) {
            unsigned rs = beg + sc[t] - v;
            rowstart[node] = (int)rs;
            cnt[node]      = (int)v;
            dinv[node]     = rsqrtf(ws[t] + 1.0f);   // +1 = self-loop
            cur[t] = rs;
        }
    }
    __syncthreads();
    for (unsigned i = beg + t; i < end; i += 256) {
        int2 ep = eparts[i];
        int n = (ep.x >> 20) & 127;
        unsigned pos = atomicAdd(&cur[n], 1u);       // LDS atomic
        efinal[pos] = ep;
    }
}

__global__ __launch_bounds__(256) void k_norm2(const unsigned* __restrict__ cbase,
                                               const float* __restrict__ dinv,
                                               int2* __restrict__ efinal) {
    int ch = blockIdx.x;
    unsigned beg = cbase[ch], end = cbase[ch + 1];
    for (unsigned i = beg + threadIdx.x; i < end; i += 256) {
        int2 ep = efinal[i];
        int s = ep.x & 0xFFFFF;
        int d = ch * 128 + ((ep.x >> 20) & 127);
        float nrm = dinv[s] * __int_as_float(ep.y) * dinv[d];
        efinal[i] = make_int2(s, __float_as_int(nrm));
    }
}

// ---------------- W -> transposed, XOR-swizzled bf16 hi/lo image ----------------

__global__ __launch_bounds__(128) void k_wconv(const float* __restrict__ W0,
                                               const float* __restrict__ W1,
                                               const float* __restrict__ W2,
                                               unsigned short* __restrict__ hiimg,
                                               unsigned short* __restrict__ loimg) {
    const float* W = (blockIdx.y == 0) ? W0 : (blockIdx.y == 1) ? W1 : W2;
    int k = blockIdx.x;
    int j = threadIdx.x;
    float v = W[k * 128 + j];
    unsigned short hi = f2bf(v);
    unsigned short lo = f2bf(v - bf2f(hi));
    unsigned off = (((unsigned)j * 256u + (unsigned)k * 2u) ^ (((unsigned)(j & 7)) << 4)) >> 1;
    hiimg[(size_t)blockIdx.y * 16384 + off] = hi;
    loimg[(size_t)blockIdx.y * 16384 + off] = lo;
}

// ---------------- MFMA GEMM: out_bf16[N,128] = A[N,128] @ W[128,128] ----------------

template <bool BF16IN>
__global__ __launch_bounds__(256) void k_gemm_mfma(const void* __restrict__ Ain,
                                                   const unsigned short* __restrict__ hiimg,
                                                   const unsigned short* __restrict__ loimg,
                                                   unsigned short* __restrict__ outb) {
    __shared__ unsigned short sW[2][16384];     // 64 KB pre-swizzled hi/lo
    __shared__ unsigned short sD[4][16 * 128];  // 16 KB per-wave D repack

    {
        f32x4* d0 = (f32x4*)&sW[0][0];
        f32x4* d1 = (f32x4*)&sW[1][0];
        const f32x4* s0 = (const f32x4*)hiimg;
        const f32x4* s1 = (const f32x4*)loimg;
        for (int t = threadIdx.x; t < 2048; t += 256) { d0[t] = s0[t]; d1[t] = s1[t]; }
    }
    __syncthreads();

    int l  = threadIdx.x & 63;
    int w  = threadIdx.x >> 6;
    int lr = l & 15;
    int kq = l >> 4;
    int row = blockIdx.x * 64 + w * 16 + lr;
    bool valid = row < NN;

    f32x4 acc[8];
#pragma unroll
    for (int c = 0; c < 8; ++c) acc[c] = (f32x4){0.f, 0.f, 0.f, 0.f};

#pragma unroll
    for (int kk = 0; kk < 4; ++kk) {
        short8 ahi = {}, alo = {};
        if (BF16IN) {
            if (valid)
                ahi = *(const short8*)((const unsigned short*)Ain + (size_t)row * NF + kk * 32 + kq * 8);
        } else {
            float av[8];
            if (valid) {
                const f32x4* p = (const f32x4*)((const float*)Ain + (size_t)row * NF + kk * 32 + kq * 8);
                f32x4 a0 = p[0], a1 = p[1];
                av[0] = a0.x; av[1] = a0.y; av[2] = a0.z; av[3] = a0.w;
                av[4] = a1.x; av[5] = a1.y; av[6] = a1.z; av[7] = a1.w;
            } else {
#pragma unroll
                for (int j = 0; j < 8; ++j) av[j] = 0.f;
            }
#pragma unroll
            for (int j = 0; j < 8; ++j) {
                unsigned short h = f2bf(av[j]);
                ahi[j] = (short)h;
                alo[j] = (short)f2bf(av[j] - bf2f(h));
            }
        }
#pragma unroll
        for (int c = 0; c < 8; ++c) {
            int j = c * 16 + lr;
            unsigned off = ((unsigned)(j * 256 + kk * 64 + kq * 16)) ^ (((unsigned)(j & 7)) << 4);
            short8 bhi = *(const short8*)((const char*)&sW[0][0] + off);
            short8 blo = *(const short8*)((const char*)&sW[1][0] + off);
            acc[c] = __builtin_amdgcn_mfma_f32_16x16x32_bf16(ahi, bhi, acc[c], 0, 0, 0);
            if (!BF16IN)
                acc[c] = __builtin_amdgcn_mfma_f32_16x16x32_bf16(alo, bhi, acc[c], 0, 0, 0);
            acc[c] = __builtin_amdgcn_mfma_f32_16x16x32_bf16(ahi, blo, acc[c], 0, 0, 0);
        }
    }

#pragma unroll
    for (int r = 0; r < 4; ++r)
#pragma unroll
        for (int c = 0; c < 8; ++c)
            sD[w][(kq * 4 + r) * 128 + c * 16 + lr] = f2bf(acc[c][r]);

    int row0w = blockIdx.x * 64 + w * 16;
#pragma unroll
    for (int i = 0; i < 4; ++i) {
        int ci = l + 64 * i;
        int rr = ci >> 4, c8 = ci & 15;
        if (row0w + rr < NN)
            *(short8*)(outb + (size_t)(row0w + rr) * NF + c8 * 8) =
                *(const short8*)&sD[w][rr * 128 + c8 * 8];
    }
}

// ---------------- CSR gather (bf16 h) + self-loop + bias + relu ----------------
// One wave per node; 2 edges per step: half-wave (32 lanes) per edge, 8 B/lane
// (uint2). Halves combined at the end via __shfl_xor(32). Unroll-8 = 16 edges
// and 16 outstanding 512B-wave loads in flight.

__global__ __launch_bounds__(256) void k_gather(const int* __restrict__ rowstart,
                                                const int* __restrict__ cnt,
                                                const int2* __restrict__ epair,
                                                const unsigned short* __restrict__ h,
                                                const float* __restrict__ dinv,
                                                const float* __restrict__ b,
                                                unsigned short* __restrict__ outp) {
    int node = blockIdx.x * 4 + (threadIdx.x >> 6);
    int lane = threadIdx.x & 63;
    int half = lane >> 5;        // which of the 2 concurrent edges
    int hl   = lane & 31;        // lane within half: owns feats 4hl..4hl+3
    int beg = rowstart[node];
    int n   = cnt[node];
    const uint2* h64 = (const uint2*)h;   // row stride = 32 uint2

    f32x4 accA = {0.f, 0.f, 0.f, 0.f};
    f32x4 accB = {0.f, 0.f, 0.f, 0.f};

    int k = 0;
    for (; k + 16 <= n; k += 16) {
        int2 e0 = epair[beg + k + 0  + half];
        int2 e1 = epair[beg + k + 2  + half];
        int2 e2 = epair[beg + k + 4  + half];
        int2 e3 = epair[beg + k + 6  + half];
        int2 e4 = epair[beg + k + 8  + half];
        int2 e5 = epair[beg + k + 10 + half];
        int2 e6 = epair[beg + k + 12 + half];
        int2 e7 = epair[beg + k + 14 + half];
        uint2 v0 = h64[(size_t)e0.x * 32 + hl];
        uint2 v1 = h64[(size_t)e1.x * 32 + hl];
        uint2 v2 = h64[(size_t)e2.x * 32 + hl];
        uint2 v3 = h64[(size_t)e3.x * 32 + hl];
        uint2 v4 = h64[(size_t)e4.x * 32 + hl];
        uint2 v5 = h64[(size_t)e5.x * 32 + hl];
        uint2 v6 = h64[(size_t)e6.x * 32 + hl];
        uint2 v7 = h64[(size_t)e7.x * 32 + hl];
        float w0 = __int_as_float(e0.y), w1 = __int_as_float(e1.y);
        float w2 = __int_as_float(e2.y), w3 = __int_as_float(e3.y);
        float w4 = __int_as_float(e4.y), w5 = __int_as_float(e5.y);
        float w6 = __int_as_float(e6.y), w7 = __int_as_float(e7.y);
        accA[0] += bfu_lo(v0.x) * w0; accA[1] += bfu_hi(v0.x) * w0;
        accA[2] += bfu_lo(v0.y) * w0; accA[3] += bfu_hi(v0.y) * w0;
        accB[0] += bfu_lo(v1.x) * w1; accB[1] += bfu_hi(v1.x) * w1;
        accB[2] += bfu_lo(v1.y) * w1; accB[3] += bfu_hi(v1.y) * w1;
        accA[0] += bfu_lo(v2.x) * w2; accA[1] += bfu_hi(v2.x) * w2;
        accA[2] += bfu_lo(v2.y) * w2; accA[3] += bfu_hi(v2.y) * w2;
        accB[0] += bfu_lo(v3.x) * w3; accB[1] += bfu_hi(v3.x) * w3;
        accB[2] += bfu_lo(v3.y) * w3; accB[3] += bfu_hi(v3.y) * w3;
        accA[0] += bfu_lo(v4.x) * w4; accA[1] += bfu_hi(v4.x) * w4;
        accA[2] += bfu_lo(v4.y) * w4; accA[3] += bfu_hi(v4.y) * w4;
        accB[0] += bfu_lo(v5.x) * w5; accB[1] += bfu_hi(v5.x) * w5;
        accB[2] += bfu_lo(v5.y) * w5; accB[3] += bfu_hi(v5.y) * w5;
        accA[0] += bfu_lo(v6.x) * w6; accA[1] += bfu_hi(v6.x) * w6;
        accA[2] += bfu_lo(v6.y) * w6; accA[3] += bfu_hi(v6.y) * w6;
        accB[0] += bfu_lo(v7.x) * w7; accB[1] += bfu_hi(v7.x) * w7;
        accB[2] += bfu_lo(v7.y) * w7; accB[3] += bfu_hi(v7.y) * w7;
    }
    for (; k + 4 <= n; k += 4) {
        int2 e0 = epair[beg + k + 0 + half];
        int2 e1 = epair[beg + k + 2 + half];
        uint2 v0 = h64[(size_t)e0.x * 32 + hl];
        uint2 v1 = h64[(size_t)e1.x * 32 + hl];
        float w0 = __int_as_float(e0.y), w1 = __int_as_float(e1.y);
        accA[0] += bfu_lo(v0.x) * w0; accA[1] += bfu_hi(v0.x) * w0;
        accA[2] += bfu_lo(v0.y) * w0; accA[3] += bfu_hi(v0.y) * w0;
        accB[0] += bfu_lo(v1.x) * w1; accB[1] += bfu_hi(v1.x) * w1;
        accB[2] += bfu_lo(v1.y) * w1; accB[3] += bfu_hi(v1.y) * w1;
    }
    for (; k < n; k += 2) {
        int idx = k + half;
        bool valid = idx < n;
        int2 e0 = epair[beg + (valid ? idx : 0)];
        float w0 = valid ? __int_as_float(e0.y) : 0.f;
        uint2 v0 = h64[(size_t)e0.x * 32 + hl];
        accA[0] += bfu_lo(v0.x) * w0; accA[1] += bfu_hi(v0.x) * w0;
        accA[2] += bfu_lo(v0.y) * w0; accA[3] += bfu_hi(v0.y) * w0;
    }

    // combine banks + opposite half-wave
    f32x4 s;
#pragma unroll
    for (int i = 0; i < 4; ++i) {
        float v = accA[i] + accB[i];
        s[i] = v + __shfl_xor(v, 32, 64);
    }

    float di = dinv[node];
    float d2 = di * di;
    uint2 hv = h64[(size_t)node * 32 + hl];
    f32x4 bb = ((const f32x4*)b)[hl];
    float o0 = fmaxf(s[0] + bfu_lo(hv.x) * d2 + bb[0], 0.f);
    float o1 = fmaxf(s[1] + bfu_hi(hv.x) * d2 + bb[1], 0.f);
    float o2 = fmaxf(s[2] + bfu_lo(hv.y) * d2 + bb[2], 0.f);
    float o3 = fmaxf(s[3] + bfu_hi(hv.y) * d2 + bb[3], 0.f);
    if (half == 0) {
        uint2 ov;
        ov.x = bfu_pack(o0, o1);
        ov.y = bfu_pack(o2, o3);
        ((uint2*)outp)[(size_t)node * 32 + hl] = ov;
    }
}

// ---------------- global mean pool (sorted batch, segmented, bf16 in) ----------------

__global__ __launch_bounds__(256) void k_pool(const unsigned short* __restrict__ h,
                                              const int* __restrict__ batch,
                                              float* __restrict__ gsum,
                                              float* __restrict__ gcnt) {
    int wid  = blockIdx.x * 4 + (threadIdx.x >> 6);
    int lane = threadIdx.x & 63;
    int n0 = wid * 16;
    if (n0 >= NN) return;
    const unsigned* h32 = (const unsigned*)h;

    float ax = 0.f, ay = 0.f;
    int cur = batch[n0];
    int nodes = 0;
    for (int t = 0; t < 16 && n0 + t < NN; ++t) {
        int g = batch[n0 + t];
        if (g != cur) {
            atomicAdd(&gsum[(size_t)cur * NF + lane * 2 + 0], ax);
            atomicAdd(&gsum[(size_t)cur * NF + lane * 2 + 1], ay);
            if (lane == 0) atomicAdd(&gcnt[cur], (float)nodes);
            ax = 0.f; ay = 0.f; nodes = 0; cur = g;
        }
        unsigned v = h32[(size_t)(n0 + t) * 64 + lane];
        ax += bfu_lo(v); ay += bfu_hi(v);
        ++nodes;
    }
    atomicAdd(&gsum[(size_t)cur * NF + lane * 2 + 0], ax);
    atomicAdd(&gsum[(size_t)cur * NF + lane * 2 + 1], ay);
    if (lane == 0) atomicAdd(&gcnt[cur], (float)nodes);
}

// ---------------- head: MLP + log_softmax ----------------

__global__ __launch_bounds__(128) void k_head(const float* __restrict__ gsum,
                                              const float* __restrict__ gcnt,
                                              const float* __restrict__ Wl1,
                                              const float* __restrict__ bl1,
                                              const float* __restrict__ Wl2,
                                              const float* __restrict__ bl2,
                                              float* __restrict__ out) {
    __shared__ float sg[128];
    __shared__ float sh[128];
    __shared__ float slog[16];
    int g = blockIdx.x;
    int t = threadIdx.x;
    float cntv = fmaxf(gcnt[g], 1.0f);
    sg[t] = gsum[(size_t)g * NF + t] / cntv;
    __syncthreads();
    float acc = bl1[t];
    for (int k = 0; k < 128; ++k) acc += sg[k] * Wl1[k * 128 + t];
    sh[t] = fmaxf(acc, 0.f);
    __syncthreads();
    if (t < NC) {
        float a = bl2[t];
        for (int k = 0; k < 128; ++k) a += sh[k] * Wl2[k * NC + t];
        slog[t] = a;
    }
    __syncthreads();
    if (t < NC) {
        float m = -1e30f;
        for (int c = 0; c < NC; ++c) m = fmaxf(m, slog[c]);
        float s = 0.f;
        for (int c = 0; c < NC; ++c) s += expf(slog[c] - m);
        out[(size_t)g * NC + t] = slog[t] - m - logf(s);
    }
}

// ---------------- launch ----------------

extern "C" void kernel_launch(void* const* d_in, const int* in_sizes, int n_in,
                              void* d_out, int out_size, void* d_ws, size_t ws_size,
                              hipStream_t stream) {
    const float* x     = (const float*)d_in[0];
    const int*   ei    = (const int*)d_in[1];
    const float* ew    = (const float*)d_in[2];
    const int*   batch = (const int*)d_in[3];
    const float* W1  = (const float*)d_in[4];
    const float* b1  = (const float*)d_in[5];
    const float* W2  = (const float*)d_in[6];
    const float* b2  = (const float*)d_in[7];
    const float* W3  = (const float*)d_in[8];
    const float* b3  = (const float*)d_in[9];
    const float* Wl1 = (const float*)d_in[10];
    const float* bl1 = (const float*)d_in[11];
    const float* Wl2 = (const float*)d_in[12];
    const float* bl2 = (const float*)d_in[13];
    float* out = (float*)d_out;

    const int* src = ei;            // edge_index[0]
    const int* dst = ei + NE;       // edge_index[1]

    // workspace carve-up (~79 MB)
    unsigned short* bufA = (unsigned short*)d_ws;                 // NN*NF bf16
    unsigned short* bufB = bufA + (size_t)NN * NF;                // NN*NF bf16
    int2*  eparts = (int2*)(bufB + (size_t)NN * NF);              // NE
    int2*  efinal = eparts + NE;                                  // NE
    unsigned* mat   = (unsigned*)(efinal + NE);                   // PBLK*NCH
    unsigned* ctot  = mat + (size_t)PBLK * NCH;                   // NCH
    unsigned* cbase = ctot + NCH;                                 // NCH+1 (pad 2)
    float* dinv = (float*)(cbase + NCH + 2);                      // NN
    float* gsum = dinv + NN;                                      // NG*NF
    float* gcnt = gsum + NG * NF;                                 // NG
    int* cnt      = (int*)(gcnt + NG);                            // NN
    int* rowstart = cnt + NN;                                     // NN
    unsigned short* hiimg = (unsigned short*)(rowstart + NN);     // 3*16384
    unsigned short* loimg = hiimg + 3 * 16384;                    // 3*16384

    // ---- CSR build (no global atomics) ----
    k_phist<<<PBLK, 256, 0, stream>>>(dst, mat);
    k_cscan<<<NCH, PBLK, 0, stream>>>(mat, ctot);
    k_cbase<<<1, 1024, 0, stream>>>(ctot, cbase);
    k_pscat<<<PBLK, 256, 0, stream>>>(src, dst, ew, mat, cbase, eparts);
    k_csort<<<NCH, 256, 0, stream>>>(cbase, eparts, efinal, rowstart, cnt, dinv);
    k_norm2<<<NCH, 256, 0, stream>>>(cbase, dinv, efinal);

    // ---- W images ----
    k_wconv<<<dim3(128, 3), 128, 0, stream>>>(W1, W2, W3, hiimg, loimg);

    // ---- 3 GCN layers ----
    k_gemm_mfma<false><<<(NN + 63) / 64, 256, 0, stream>>>(x, hiimg, loimg, bufA);
    k_gather<<<NN / 4, 256, 0, stream>>>(rowstart, cnt, efinal, bufA, dinv, b1, bufB);
    k_gemm_mfma<true><<<(NN + 63) / 64, 256, 0, stream>>>(bufB, hiimg + 16384, loimg + 16384, bufA);
    k_gather<<<NN / 4, 256, 0, stream>>>(rowstart, cnt, efinal, bufA, dinv, b2, bufB);
    k_gemm_mfma<true><<<(NN + 63) / 64, 256, 0, stream>>>(bufB, hiimg + 32768, loimg + 32768, bufA);
    k_gather<<<NN / 4, 256, 0, stream>>>(rowstart, cnt, efinal, bufA, dinv, b3, bufB);

    // ---- global mean pool ----
    hipMemsetAsync(gsum, 0, (NG * NF + NG) * sizeof(float), stream);
    k_pool<<<(NN / 16 + 3) / 4, 256, 0, stream>>>(bufB, batch, gsum, gcnt);

    // ---- head ----
    k_head<<<NG, 128, 0, stream>>>(gsum, gcnt, Wl1, bl1, Wl2, bl2, out);
}

// Round 10
// 518.419 us; speedup vs baseline: 1.0315x; 1.0315x over previous
//
#include <hip/hip_runtime.h>
#include <hip/hip_bf16.h>

#define NN 100000
#define NE 1600000
#define NF 128
#define NG 128
#define NC 10

#define NCH 782        // 128-node chunks: 782*128 = 100096 >= NN
#define PBLK 128       // partition blocks
#define EPB 12500      // edges per partition block (128*12500 = NE exactly)

typedef short short8 __attribute__((ext_vector_type(8)));
typedef float f32x4 __attribute__((ext_vector_type(4)));

__device__ inline unsigned short f2bf(float x) {
    unsigned u = __float_as_uint(x);
    u += 0x7FFF + ((u >> 16) & 1);          // round-to-nearest-even
    return (unsigned short)(u >> 16);
}
__device__ inline float bf2f(unsigned short h) {
    return __uint_as_float(((unsigned)h) << 16);
}
__device__ inline float bfu_lo(unsigned v) { return __uint_as_float(v << 16); }
__device__ inline float bfu_hi(unsigned v) { return __uint_as_float(v & 0xffff0000u); }
__device__ inline unsigned bfu_pack(float lo, float hi) {
    return (unsigned)f2bf(lo) | ((unsigned)f2bf(hi) << 16);
}

// ================= CSR build: two-level counting sort, NO global atomics =================

__global__ __launch_bounds__(256) void k_phist(const int* __restrict__ dst,
                                               unsigned* __restrict__ mat) {
    __shared__ unsigned lh[NCH];
    for (int i = threadIdx.x; i < NCH; i += 256) lh[i] = 0;
    __syncthreads();
    int base = blockIdx.x * EPB;
    for (int i = threadIdx.x; i < EPB; i += 256)
        atomicAdd(&lh[dst[base + i] >> 7], 1u);
    __syncthreads();
    for (int i = threadIdx.x; i < NCH; i += 256)
        mat[(size_t)blockIdx.x * NCH + i] = lh[i];
}

__global__ __launch_bounds__(PBLK) void k_cscan(unsigned* __restrict__ mat,
                                                unsigned* __restrict__ ctot) {
    __shared__ unsigned s[PBLK];
    int ch = blockIdx.x;
    int t  = threadIdx.x;
    unsigned v = mat[(size_t)t * NCH + ch];
    s[t] = v;
    __syncthreads();
    for (int off = 1; off < PBLK; off <<= 1) {
        unsigned u = (t >= off) ? s[t - off] : 0;
        __syncthreads();
        s[t] += u;
        __syncthreads();
    }
    mat[(size_t)t * NCH + ch] = s[t] - v;
    if (t == PBLK - 1) ctot[ch] = s[t];
}

__global__ __launch_bounds__(1024) void k_cbase(const unsigned* __restrict__ ctot,
                                                unsigned* __restrict__ cbase) {
    __shared__ unsigned s[1024];
    int t = threadIdx.x;
    unsigned v = (t < NCH) ? ctot[t] : 0;
    s[t] = v;
    __syncthreads();
    for (int off = 1; off < 1024; off <<= 1) {
        unsigned u = (t >= off) ? s[t - off] : 0;
        __syncthreads();
        s[t] += u;
        __syncthreads();
    }
    if (t < NCH) cbase[t] = s[t] - v;
    if (t == NCH - 1) cbase[NCH] = s[t];
}

__global__ __launch_bounds__(256) void k_pscat(const int* __restrict__ src,
                                               const int* __restrict__ dst,
                                               const float* __restrict__ ew,
                                               const unsigned* __restrict__ mat,
                                               const unsigned* __restrict__ cbase,
                                               int2* __restrict__ eparts) {
    __shared__ unsigned cur[NCH];
    for (int i = threadIdx.x; i < NCH; i += 256)
        cur[i] = cbase[i] + mat[(size_t)blockIdx.x * NCH + i];
    __syncthreads();
    int base = blockIdx.x * EPB;
    for (int i = threadIdx.x; i < EPB; i += 256) {
        int e = base + i;
        int d = dst[e], s = src[e];
        float w = ew[e];
        unsigned pos = atomicAdd(&cur[d >> 7], 1u);   // LDS atomic
        eparts[pos] = make_int2(s | ((d & 127) << 20), __float_as_int(w));
    }
}

__global__ __launch_bounds__(256) void k_csort(const unsigned* __restrict__ cbase,
                                               const int2* __restrict__ eparts,
                                               int2* __restrict__ efinal,
                                               int* __restrict__ rowstart,
                                               int* __restrict__ cnt,
                                               float* __restrict__ dinv) {
    __shared__ unsigned nh[128];
    __shared__ float    ws[128];
    __shared__ unsigned sc[128];
    __shared__ unsigned cur[128];
    int ch = blockIdx.x;
    unsigned beg = cbase[ch], end = cbase[ch + 1];
    int t = threadIdx.x;
    if (t < 128) { nh[t] = 0; ws[t] = 0.f; }
    __syncthreads();
    for (unsigned i = beg + t; i < end; i += 256) {
        int2 ep = eparts[i];
        int n = (ep.x >> 20) & 127;
        atomicAdd(&nh[n], 1u);
        atomicAdd(&ws[n], __int_as_float(ep.y));
    }
    __syncthreads();
    unsigned v = (t < 128) ? nh[t] : 0;
    if (t < 128) sc[t] = v;
    __syncthreads();
    for (int off = 1; off < 128; off <<= 1) {
        unsigned u = (t >= off && t < 128) ? sc[t - off] : 0;
        __syncthreads();
        if (t < 128) sc[t] += u;
        __syncthreads();
    }
    if (t < 128) {
        int node = ch * 128 + t;
        if (node < NN) {
            unsigned rs = beg + sc[t] - v;
            rowstart[node] = (int)rs;
            cnt[node]      = (int)v;
            dinv[node]     = rsqrtf(ws[t] + 1.0f);   // +1 = self-loop
            cur[t] = rs;
        }
    }
    __syncthreads();
    for (unsigned i = beg + t; i < end; i += 256) {
        int2 ep = eparts[i];
        int n = (ep.x >> 20) & 127;
        unsigned pos = atomicAdd(&cur[n], 1u);       // LDS atomic
        efinal[pos] = ep;
    }
}

__global__ __launch_bounds__(256) void k_norm2(const unsigned* __restrict__ cbase,
                                               const float* __restrict__ dinv,
                                               int2* __restrict__ efinal) {
    int ch = blockIdx.x;
    unsigned beg = cbase[ch], end = cbase[ch + 1];
    for (unsigned i = beg + threadIdx.x; i < end; i += 256) {
        int2 ep = efinal[i];
        int s = ep.x & 0xFFFFF;
        int d = ch * 128 + ((ep.x >> 20) & 127);
        float nrm = dinv[s] * __int_as_float(ep.y) * dinv[d];
        efinal[i] = make_int2(s, __float_as_int(nrm));
    }
}

// ---------------- x (f32) -> bf16 table, once ----------------

__global__ __launch_bounds__(256) void k_xconv(const float* __restrict__ x,
                                               unsigned* __restrict__ xb) {
    int i = blockIdx.x * 256 + threadIdx.x;    // uint2-of-bf16 granularity (4 floats)
    if (i < NN * NF / 4) {
        f32x4 v = ((const f32x4*)x)[i];
        uint2 o;
        o.x = bfu_pack(v[0], v[1]);
        o.y = bfu_pack(v[2], v[3]);
        ((uint2*)xb)[i] = o;
    }
}

// ---------------- W -> transposed, XOR-swizzled bf16 hi/lo image ----------------

__global__ __launch_bounds__(128) void k_wconv(const float* __restrict__ W0,
                                               const float* __restrict__ W1,
                                               const float* __restrict__ W2,
                                               unsigned short* __restrict__ hiimg,
                                               unsigned short* __restrict__ loimg) {
    const float* W = (blockIdx.y == 0) ? W0 : (blockIdx.y == 1) ? W1 : W2;
    int k = blockIdx.x;
    int j = threadIdx.x;
    float v = W[k * 128 + j];
    unsigned short hi = f2bf(v);
    unsigned short lo = f2bf(v - bf2f(hi));
    unsigned off = (((unsigned)j * 256u + (unsigned)k * 2u) ^ (((unsigned)(j & 7)) << 4)) >> 1;
    hiimg[(size_t)blockIdx.y * 16384 + off] = hi;
    loimg[(size_t)blockIdx.y * 16384 + off] = lo;
}

// ---------------- MFMA GEMM: out_bf16[N,128] = A_bf16[N,128] @ W[128,128] ----------------
// 256 rows/block (W-stage amortized 4x); wave w does 4 tiles of 16 rows.
// 2 MFMA passes: ahi*bhi + ahi*blo (A exact bf16, W hi/lo split).

__global__ __launch_bounds__(256) void k_gemm_mfma(const unsigned short* __restrict__ A,
                                                   const unsigned short* __restrict__ hiimg,
                                                   const unsigned short* __restrict__ loimg,
                                                   unsigned short* __restrict__ outb) {
    __shared__ unsigned short sW[2][16384];     // 64 KB pre-swizzled hi/lo
    __shared__ unsigned short sD[4][16 * 128];  // 16 KB per-wave D repack

    {
        f32x4* d0 = (f32x4*)&sW[0][0];
        f32x4* d1 = (f32x4*)&sW[1][0];
        const f32x4* s0 = (const f32x4*)hiimg;
        const f32x4* s1 = (const f32x4*)loimg;
        for (int t = threadIdx.x; t < 2048; t += 256) { d0[t] = s0[t]; d1[t] = s1[t]; }
    }
    __syncthreads();

    int l  = threadIdx.x & 63;
    int w  = threadIdx.x >> 6;
    int lr = l & 15;
    int kq = l >> 4;

#pragma unroll
    for (int rt = 0; rt < 4; ++rt) {
        int row0t = blockIdx.x * 256 + w * 64 + rt * 16;
        int row = row0t + lr;
        bool valid = row < NN;

        f32x4 acc[8];
#pragma unroll
        for (int c = 0; c < 8; ++c) acc[c] = (f32x4){0.f, 0.f, 0.f, 0.f};

#pragma unroll
        for (int kk = 0; kk < 4; ++kk) {
            short8 ahi = {};
            if (valid)
                ahi = *(const short8*)(A + (size_t)row * NF + kk * 32 + kq * 8);
#pragma unroll
            for (int c = 0; c < 8; ++c) {
                int j = c * 16 + lr;
                unsigned off = ((unsigned)(j * 256 + kk * 64 + kq * 16)) ^ (((unsigned)(j & 7)) << 4);
                short8 bhi = *(const short8*)((const char*)&sW[0][0] + off);
                short8 blo = *(const short8*)((const char*)&sW[1][0] + off);
                acc[c] = __builtin_amdgcn_mfma_f32_16x16x32_bf16(ahi, bhi, acc[c], 0, 0, 0);
                acc[c] = __builtin_amdgcn_mfma_f32_16x16x32_bf16(ahi, blo, acc[c], 0, 0, 0);
            }
        }

        // D: lane l, reg r -> row=kq*4+r, col=c*16+lr (within 16-row tile).
        // Repack via per-wave LDS tile (wave-local, no barrier), coalesced short8 stores.
#pragma unroll
        for (int r = 0; r < 4; ++r)
#pragma unroll
            for (int c = 0; c < 8; ++c)
                sD[w][(kq * 4 + r) * 128 + c * 16 + lr] = f2bf(acc[c][r]);

#pragma unroll
        for (int i = 0; i < 4; ++i) {
            int ci = l + 64 * i;
            int rr = ci >> 4, c8 = ci & 15;
            if (row0t + rr < NN)
                *(short8*)(outb + (size_t)(row0t + rr) * NF + c8 * 8) =
                    *(const short8*)&sD[w][rr * 128 + c8 * 8];
        }
    }
}

// ---------------- CSR gather (bf16 h) + self-loop + bias + relu ----------------
// One wave per node; lane owns feats (2l, 2l+1). Unroll 8 (round-8 best: 69us).

__global__ __launch_bounds__(256) void k_gather(const int* __restrict__ rowstart,
                                                const int* __restrict__ cnt,
                                                const int2* __restrict__ epair,
                                                const unsigned short* __restrict__ h,
                                                const float* __restrict__ dinv,
                                                const float* __restrict__ b,
                                                unsigned short* __restrict__ outp) {
    int node = blockIdx.x * 4 + (threadIdx.x >> 6);
    int lane = threadIdx.x & 63;
    int beg = rowstart[node];
    int n   = cnt[node];
    const unsigned* h32 = (const unsigned*)h;

    float sx0 = 0.f, sy0 = 0.f, sx1 = 0.f, sy1 = 0.f;
    float sx2 = 0.f, sy2 = 0.f, sx3 = 0.f, sy3 = 0.f;
    int k = 0;
    for (; k + 8 <= n; k += 8) {
        int2 e0 = epair[beg + k + 0];
        int2 e1 = epair[beg + k + 1];
        int2 e2 = epair[beg + k + 2];
        int2 e3 = epair[beg + k + 3];
        int2 e4 = epair[beg + k + 4];
        int2 e5 = epair[beg + k + 5];
        int2 e6 = epair[beg + k + 6];
        int2 e7 = epair[beg + k + 7];
        unsigned v0 = h32[(size_t)e0.x * 64 + lane];
        unsigned v1 = h32[(size_t)e1.x * 64 + lane];
        unsigned v2 = h32[(size_t)e2.x * 64 + lane];
        unsigned v3 = h32[(size_t)e3.x * 64 + lane];
        unsigned v4 = h32[(size_t)e4.x * 64 + lane];
        unsigned v5 = h32[(size_t)e5.x * 64 + lane];
        unsigned v6 = h32[(size_t)e6.x * 64 + lane];
        unsigned v7 = h32[(size_t)e7.x * 64 + lane];
        float w0 = __int_as_float(e0.y), w1 = __int_as_float(e1.y);
        float w2 = __int_as_float(e2.y), w3 = __int_as_float(e3.y);
        float w4 = __int_as_float(e4.y), w5 = __int_as_float(e5.y);
        float w6 = __int_as_float(e6.y), w7 = __int_as_float(e7.y);
        sx0 += bfu_lo(v0) * w0; sy0 += bfu_hi(v0) * w0;
        sx1 += bfu_lo(v1) * w1; sy1 += bfu_hi(v1) * w1;
        sx2 += bfu_lo(v2) * w2; sy2 += bfu_hi(v2) * w2;
        sx3 += bfu_lo(v3) * w3; sy3 += bfu_hi(v3) * w3;
        sx0 += bfu_lo(v4) * w4; sy0 += bfu_hi(v4) * w4;
        sx1 += bfu_lo(v5) * w5; sy1 += bfu_hi(v5) * w5;
        sx2 += bfu_lo(v6) * w6; sy2 += bfu_hi(v6) * w6;
        sx3 += bfu_lo(v7) * w7; sy3 += bfu_hi(v7) * w7;
    }
    for (; k + 4 <= n; k += 4) {
        int2 e0 = epair[beg + k + 0];
        int2 e1 = epair[beg + k + 1];
        int2 e2 = epair[beg + k + 2];
        int2 e3 = epair[beg + k + 3];
        unsigned v0 = h32[(size_t)e0.x * 64 + lane];
        unsigned v1 = h32[(size_t)e1.x * 64 + lane];
        unsigned v2 = h32[(size_t)e2.x * 64 + lane];
        unsigned v3 = h32[(size_t)e3.x * 64 + lane];
        float w0 = __int_as_float(e0.y), w1 = __int_as_float(e1.y);
        float w2 = __int_as_float(e2.y), w3 = __int_as_float(e3.y);
        sx0 += bfu_lo(v0) * w0; sy0 += bfu_hi(v0) * w0;
        sx1 += bfu_lo(v1) * w1; sy1 += bfu_hi(v1) * w1;
        sx2 += bfu_lo(v2) * w2; sy2 += bfu_hi(v2) * w2;
        sx3 += bfu_lo(v3) * w3; sy3 += bfu_hi(v3) * w3;
    }
    for (; k < n; ++k) {
        int2 e0 = epair[beg + k];
        unsigned v0 = h32[(size_t)e0.x * 64 + lane];
        float w0 = __int_as_float(e0.y);
        sx0 += bfu_lo(v0) * w0; sy0 += bfu_hi(v0) * w0;
    }
    float ax = (sx0 + sx1) + (sx2 + sx3);
    float ay = (sy0 + sy1) + (sy2 + sy3);

    float di = dinv[node];
    float d2 = di * di;
    unsigned hv = h32[(size_t)node * 64 + lane];
    float2 bb = ((const float2*)b)[lane];
    float ox = fmaxf(ax + bfu_lo(hv) * d2 + bb.x, 0.f);
    float oy = fmaxf(ay + bfu_hi(hv) * d2 + bb.y, 0.f);
    ((unsigned*)outp)[(size_t)node * 64 + lane] = bfu_pack(ox, oy);
}

// ---------------- global mean pool (sorted batch, segmented, bf16 in) ----------------

__global__ __launch_bounds__(256) void k_pool(const unsigned short* __restrict__ h,
                                              const int* __restrict__ batch,
                                              float* __restrict__ gsum,
                                              float* __restrict__ gcnt) {
    int wid  = blockIdx.x * 4 + (threadIdx.x >> 6);
    int lane = threadIdx.x & 63;
    int n0 = wid * 16;
    if (n0 >= NN) return;
    const unsigned* h32 = (const unsigned*)h;

    float ax = 0.f, ay = 0.f;
    int cur = batch[n0];
    int nodes = 0;
    for (int t = 0; t < 16 && n0 + t < NN; ++t) {
        int g = batch[n0 + t];
        if (g != cur) {
            atomicAdd(&gsum[(size_t)cur * NF + lane * 2 + 0], ax);
            atomicAdd(&gsum[(size_t)cur * NF + lane * 2 + 1], ay);
            if (lane == 0) atomicAdd(&gcnt[cur], (float)nodes);
            ax = 0.f; ay = 0.f; nodes = 0; cur = g;
        }
        unsigned v = h32[(size_t)(n0 + t) * 64 + lane];
        ax += bfu_lo(v); ay += bfu_hi(v);
        ++nodes;
    }
    atomicAdd(&gsum[(size_t)cur * NF + lane * 2 + 0], ax);
    atomicAdd(&gsum[(size_t)cur * NF + lane * 2 + 1], ay);
    if (lane == 0) atomicAdd(&gcnt[cur], (float)nodes);
}

// ---------------- head: MLP + log_softmax ----------------

__global__ __launch_bounds__(128) void k_head(const float* __restrict__ gsum,
                                              const float* __restrict__ gcnt,
                                              const float* __restrict__ Wl1,
                                              const float* __restrict__ bl1,
                                              const float* __restrict__ Wl2,
                                              const float* __restrict__ bl2,
                                              float* __restrict__ out) {
    __shared__ float sg[128];
    __shared__ float sh[128];
    __shared__ float slog[16];
    int g = blockIdx.x;
    int t = threadIdx.x;
    float cntv = fmaxf(gcnt[g], 1.0f);
    sg[t] = gsum[(size_t)g * NF + t] / cntv;
    __syncthreads();
    float acc = bl1[t];
    for (int k = 0; k < 128; ++k) acc += sg[k] * Wl1[k * 128 + t];
    sh[t] = fmaxf(acc, 0.f);
    __syncthreads();
    if (t < NC) {
        float a = bl2[t];
        for (int k = 0; k < 128; ++k) a += sh[k] * Wl2[k * NC + t];
        slog[t] = a;
    }
    __syncthreads();
    if (t < NC) {
        float m = -1e30f;
        for (int c = 0; c < NC; ++c) m = fmaxf(m, slog[c]);
        float s = 0.f;
        for (int c = 0; c < NC; ++c) s += expf(slog[c] - m);
        out[(size_t)g * NC + t] = slog[t] - m - logf(s);
    }
}

// ---------------- launch ----------------

extern "C" void kernel_launch(void* const* d_in, const int* in_sizes, int n_in,
                              void* d_out, int out_size, void* d_ws, size_t ws_size,
                              hipStream_t stream) {
    const float* x     = (const float*)d_in[0];
    const int*   ei    = (const int*)d_in[1];
    const float* ew    = (const float*)d_in[2];
    const int*   batch = (const int*)d_in[3];
    const float* W1  = (const float*)d_in[4];
    const float* b1  = (const float*)d_in[5];
    const float* W2  = (const float*)d_in[6];
    const float* b2  = (const float*)d_in[7];
    const float* W3  = (const float*)d_in[8];
    const float* b3  = (const float*)d_in[9];
    const float* Wl1 = (const float*)d_in[10];
    const float* bl1 = (const float*)d_in[11];
    const float* Wl2 = (const float*)d_in[12];
    const float* bl2 = (const float*)d_in[13];
    float* out = (float*)d_out;

    const int* src = ei;            // edge_index[0]
    const int* dst = ei + NE;       // edge_index[1]

    // workspace carve-up (~105 MB)
    unsigned short* bufA = (unsigned short*)d_ws;                 // NN*NF bf16
    unsigned short* bufB = bufA + (size_t)NN * NF;                // NN*NF bf16
    int2*  eparts = (int2*)(bufB + (size_t)NN * NF);              // NE
    int2*  efinal = eparts + NE;                                  // NE
    unsigned* mat   = (unsigned*)(efinal + NE);                   // PBLK*NCH
    unsigned* ctot  = mat + (size_t)PBLK * NCH;                   // NCH
    unsigned* cbase = ctot + NCH;                                 // NCH+1 (pad 2)
    float* dinv = (float*)(cbase + NCH + 2);                      // NN
    float* gsum = dinv + NN;                                      // NG*NF
    float* gcnt = gsum + NG * NF;                                 // NG
    int* cnt      = (int*)(gcnt + NG);                            // NN
    int* rowstart = cnt + NN;                                     // NN
    unsigned short* hiimg = (unsigned short*)(rowstart + NN);     // 3*16384
    unsigned short* loimg = hiimg + 3 * 16384;                    // 3*16384
    unsigned short* bufX  = loimg + 3 * 16384;                    // NN*NF bf16 (x)

    // ---- CSR build (no global atomics) ----
    k_phist<<<PBLK, 256, 0, stream>>>(dst, mat);
    k_cscan<<<NCH, PBLK, 0, stream>>>(mat, ctot);
    k_cbase<<<1, 1024, 0, stream>>>(ctot, cbase);
    k_pscat<<<PBLK, 256, 0, stream>>>(src, dst, ew, mat, cbase, eparts);
    k_csort<<<NCH, 256, 0, stream>>>(cbase, eparts, efinal, rowstart, cnt, dinv);
    k_norm2<<<NCH, 256, 0, stream>>>(cbase, dinv, efinal);

    // ---- input/weight conversions ----
    k_xconv<<<(NN * NF / 4 + 255) / 256, 256, 0, stream>>>(x, (unsigned*)bufX);
    k_wconv<<<dim3(128, 3), 128, 0, stream>>>(W1, W2, W3, hiimg, loimg);

    // ---- 3 GCN layers ----
    k_gemm_mfma<<<(NN + 255) / 256, 256, 0, stream>>>(bufX, hiimg, loimg, bufA);
    k_gather<<<NN / 4, 256, 0, stream>>>(rowstart, cnt, efinal, bufA, dinv, b1, bufB);
    k_gemm_mfma<<<(NN + 255) / 256, 256, 0, stream>>>(bufB, hiimg + 16384, loimg + 16384, bufA);
    k_gather<<<NN / 4, 256, 0, stream>>>(rowstart, cnt, efinal, bufA, dinv, b2, bufB);
    k_gemm_mfma<<<(NN + 255) / 256, 256, 0, stream>>>(bufB, hiimg + 32768, loimg + 32768, bufA);
    k_gather<<<NN / 4, 256, 0, stream>>>(rowstart, cnt, efinal, bufA, dinv, b3, bufB);

    // ---- global mean pool ----
    hipMemsetAsync(gsum, 0, (NG * NF + NG) * sizeof(float), stream);
    k_pool<<<(NN / 16 + 3) / 4, 256, 0, stream>>>(bufB, batch, gsum, gcnt);

    // ---- head ----
    k_head<<<NG, 128, 0, stream>>>(gsum, gcnt, Wl1, bl1, Wl2, bl2, out);
}